// Round 14
// baseline (72.911 us; speedup 1.0000x reference)
//
#include <hip/hip_runtime.h>

#define KS    13
#define HALF  6
#define TY    32              // output rows per strip
#define SEG   256             // output cols per wave-block
#define SW    272             // staged floats per row: 8 halo + 256 + 8
#define NITER (TY + 12)       // 44 staged rows
#define NK    (NITER / 2)     // 22 iterations, 2 rows each
#define IMG_H 1024
#define IMG_W 1024

__device__ __forceinline__ int reflect_idx(int i, int n) {
    if (i < 0) i = -i;
    if (i >= n) i = 2 * n - 2 - i;
    return i;
}

struct Ctx {
    const float* xin;
    float*       o;
    float        g[KS];
    int          lane;     // 0..63; output cols c0+4*lane..+3
    int          c0;       // segment's first output col
    int          r0;       // strip's first output row
};

// Load one granule (4 floats) of a row slice, reflecting at image columns.
__device__ __forceinline__ float4 load_gran(const float* rowp, int gc0) {
    if (gc0 >= 0 && gc0 <= IMG_W - 4)
        return *reinterpret_cast<const float4*>(rowp + gc0);
    float4 v;
    v.x = rowp[reflect_idx(gc0 + 0, IMG_W)];
    v.y = rowp[reflect_idx(gc0 + 1, IMG_W)];
    v.z = rowp[reflect_idx(gc0 + 2, IMG_W)];
    v.w = rowp[reflect_idx(gc0 + 3, IMG_W)];
    return v;
}

// H-filter one staged row slice: lane reads floats 4*lane..4*lane+19 (granules
// lane..lane+4, consecutive-lane b128 -> conflict-free), 13 taps x 4 cols.
// Branch-free: halo is pre-staged, no column reflect here.
__device__ __forceinline__ float4 h_filter(const float* srow, const Ctx& cx) {
    float f[20];
    #pragma unroll
    for (int k = 0; k < 5; ++k) {
        float4 v = *reinterpret_cast<const float4*>(srow + 4 * cx.lane + 4 * k);
        f[4*k+0] = v.x; f[4*k+1] = v.y; f[4*k+2] = v.z; f[4*k+3] = v.w;
    }
    float4 h = make_float4(0.f, 0.f, 0.f, 0.f);
    #pragma unroll
    for (int j = 0; j < KS; ++j) {
        h.x += cx.g[j] * f[2 + j];
        h.y += cx.g[j] * f[3 + j];
        h.z += cx.g[j] * f[4 + j];
        h.w += cx.g[j] * f[5 + j];
    }
    return h;
}

// Iteration k (= outer*7 + U): commit staged rows 2k,2k+1 to the (k&1) LDS pair,
// prefetch rows 2k+2,2k+3, barrier (1-wave workgroup: near-free, orders LDS),
// H-filter both rows into window slots (2U)%14,(2U+1)%14, V-filter -> 2 output rows.
// All window indices compile-time (template U) -> registers, no scratch (rule #20).
template<int U>
__device__ __forceinline__ void body2(int outer, const Ctx& cx, float (*s)[SW],
                                      float4 (&w)[14],
                                      float4& cA0, float4& cB0,
                                      float4& cA1, float4& cB1)
{
    const int k = outer * 7 + U;
    if (k >= NK) return;
    const int n0 = 2 * k;
    const int bp = (k & 1) * 2;
    const bool hasB = cx.lane < 4;       // lanes 0-3 carry granules 64..67

    // commit staged rows to the wave-private LDS pair
    *reinterpret_cast<float4*>(&s[bp + 0][4 * cx.lane]) = cA0;
    *reinterpret_cast<float4*>(&s[bp + 1][4 * cx.lane]) = cA1;
    if (hasB) {
        *reinterpret_cast<float4*>(&s[bp + 0][256 + 4 * cx.lane]) = cB0;
        *reinterpret_cast<float4*>(&s[bp + 1][256 + 4 * cx.lane]) = cB1;
    }

    // prefetch next row pair (in flight across barrier + compute; T14)
    if (k + 1 < NK) {
        const float* ra = cx.xin + (size_t)reflect_idx(cx.r0 + n0 - 4, IMG_H) * IMG_W;
        const float* rb = cx.xin + (size_t)reflect_idx(cx.r0 + n0 - 3, IMG_H) * IMG_W;
        const int gA = cx.c0 - 8 + 4 * cx.lane;
        cA0 = load_gran(ra, gA);
        cA1 = load_gran(rb, gA);
        if (hasB) {
            const int gB = cx.c0 - 8 + 4 * (64 + cx.lane);
            cB0 = load_gran(ra, gB);
            cB1 = load_gran(rb, gB);
        }
    }
    __syncthreads();

    // two H-filters into the rolling 14-slot window
    w[(2 * U) % 14]     = h_filter(s[bp + 0], cx);
    w[(2 * U + 1) % 14] = h_filter(s[bp + 1], cx);

    // two V-filters -> output rows r0+n0-12, r0+n0-11
    if (n0 >= 12) {
        float4 a0 = make_float4(0.f, 0.f, 0.f, 0.f);
        float4 a1 = make_float4(0.f, 0.f, 0.f, 0.f);
        #pragma unroll
        for (int j = 0; j < KS; ++j) {
            const float4 v0 = w[(2 * U + 2 + j) % 14];
            const float4 v1 = w[(2 * U + 3 + j) % 14];
            a0.x += cx.g[j] * v0.x;  a1.x += cx.g[j] * v1.x;
            a0.y += cx.g[j] * v0.y;  a1.y += cx.g[j] * v1.y;
            a0.z += cx.g[j] * v0.z;  a1.z += cx.g[j] * v1.z;
            a0.w += cx.g[j] * v0.w;  a1.w += cx.g[j] * v1.w;
        }
        float* d0 = cx.o + (size_t)(cx.r0 + n0 - 12) * IMG_W + cx.c0 + 4 * cx.lane;
        float* d1 = cx.o + (size_t)(cx.r0 + n0 - 11) * IMG_W + cx.c0 + 4 * cx.lane;
        *reinterpret_cast<float4*>(d0) = a0;
        *reinterpret_cast<float4*>(d1) = a1;
    }
}

// Single-wave workgroups: __syncthreads never waits on another wave -> zero
// convoy; 4096 blocks = 16 free-running waves/CU.
// No launch-bounds min-waves (R2: VGPR cap -> spill). Expect ~115 VGPR.
__global__ __launch_bounds__(64) void gauss_blur_stream(
    const float* __restrict__ x, const float* __restrict__ k2d,
    float* __restrict__ out)
{
    __shared__ float s[4][SW];   // 4352 B: two ping-pong row pairs (wave-private)

    Ctx cx;
    cx.lane = threadIdx.x;
    cx.c0   = blockIdx.x * SEG;
    cx.r0   = blockIdx.y * TY;
    const int img = blockIdx.z;
    cx.xin = x + (size_t)img * IMG_H * IMG_W;
    cx.o   = out + (size_t)img * IMG_H * IMG_W;

    // 1D taps: k2d = outer(g,g) exactly, g[i] = k2d[i][6]/sqrt(k2d[6][6])
    {
        float c   = k2d[HALF * KS + HALF];
        float inv = 1.0f / sqrtf(c);
        #pragma unroll
        for (int j = 0; j < KS; ++j) cx.g[j] = k2d[j * KS + HALF] * inv;
    }

    // preload rows 0,1 (input rows r0-6, r0-5)
    const bool hasB = cx.lane < 4;
    const int  gA   = cx.c0 - 8 + 4 * cx.lane;
    const int  gB   = cx.c0 - 8 + 4 * (64 + cx.lane);
    const float* ra = cx.xin + (size_t)reflect_idx(cx.r0 - 6, IMG_H) * IMG_W;
    const float* rb = cx.xin + (size_t)reflect_idx(cx.r0 - 5, IMG_H) * IMG_W;
    float4 cA0 = load_gran(ra, gA);
    float4 cA1 = load_gran(rb, gA);
    float4 cB0 = hasB ? load_gran(ra, gB) : make_float4(0,0,0,0);
    float4 cB1 = hasB ? load_gran(rb, gB) : make_float4(0,0,0,0);

    float4 w[14];
    for (int outer = 0; outer < 4; ++outer) {   // 4*7 = 28 bodies, guard k<22
        body2<0>(outer, cx, s, w, cA0, cB0, cA1, cB1);
        body2<1>(outer, cx, s, w, cA0, cB0, cA1, cB1);
        body2<2>(outer, cx, s, w, cA0, cB0, cA1, cB1);
        body2<3>(outer, cx, s, w, cA0, cB0, cA1, cB1);
        body2<4>(outer, cx, s, w, cA0, cB0, cA1, cB1);
        body2<5>(outer, cx, s, w, cA0, cB0, cA1, cB1);
        body2<6>(outer, cx, s, w, cA0, cB0, cA1, cB1);
    }
}

extern "C" void kernel_launch(void* const* d_in, const int* in_sizes, int n_in,
                              void* d_out, int out_size, void* d_ws, size_t ws_size,
                              hipStream_t stream) {
    const float* x   = (const float*)d_in[0];
    const float* k2d = (const float*)d_in[1];
    float*       out = (float*)d_out;

    dim3 grid(IMG_W / SEG, IMG_H / TY, 32);   // 4 x 32 x 32 = 4096 single-wave blocks
    gauss_blur_stream<<<grid, 64, 0, stream>>>(x, k2d, out);
}

// Round 15
// 54.229 us; speedup vs baseline: 1.3445x; 1.3445x over previous
//
#include <hip/hip_runtime.h>

#define KS    13
#define HALF  6
#define TY    32              // output rows per strip (R13 geometry — best measured)
#define NITER (TY + 12)       // 44 staged rows
#define NK    (NITER / 4)     // 11 iterations, 4 rows per barrier
#define IMG_H 1024
#define IMG_W 1024

__device__ __forceinline__ int reflect_idx(int i, int n) {
    if (i < 0) i = -i;
    if (i >= n) i = 2 * n - 2 - i;
    return i;
}

struct Ctx {
    const float* xin;
    float*       o;
    float        g[KS];
    int          t;        // thread's column granule: cols 4t..4t+3
    int          r0;       // strip's first output row
    bool         interior; // 2 <= t <= 253 : LDS window read needs no column reflect
};

// H-filter one staged row from LDS: 20-float window -> 4 outputs.
__device__ __forceinline__ float4 h_filter(const float* srow, const Ctx& cx) {
    float f[20];
    if (cx.interior) {
        #pragma unroll
        for (int k = 0; k < 5; ++k) {
            float4 v = *reinterpret_cast<const float4*>(srow + 4 * cx.t - 8 + 4 * k);
            f[4*k+0] = v.x; f[4*k+1] = v.y; f[4*k+2] = v.z; f[4*k+3] = v.w;
        }
    } else {
        #pragma unroll
        for (int k = 0; k < 20; ++k)
            f[k] = srow[reflect_idx(4 * cx.t - 8 + k, IMG_W)];
    }
    float4 h = make_float4(0.f, 0.f, 0.f, 0.f);
    #pragma unroll
    for (int j = 0; j < KS; ++j) {
        h.x += cx.g[j] * f[2 + j];
        h.y += cx.g[j] * f[3 + j];
        h.z += cx.g[j] * f[4 + j];
        h.w += cx.g[j] * f[5 + j];
    }
    return h;
}

// Iteration k (= outer*4 + U, so k%4 == U): stages raw rows 4k..4k+3 (input rows
// r0+n-6) into the (k&1) LDS quad, prefetches rows 4k+4..4k+7, ONE barrier,
// H-filters 4 rows into window slots (4U+m)%16, then (k>=3) V-filters -> output
// rows r0+4k-12..+3. All window indices compile-time (rule #20).
// WAR safety: iter k's reads precede barrier_{k+1}; iter k+2's rewrites of this
// quad follow barrier_{k+1} (ping-pong proof as in R13).
template<int U>
__device__ __forceinline__ void body4(int outer, const Ctx& cx, float (*s)[IMG_W],
                                      float4 (&w)[16],
                                      float4& c0, float4& c1, float4& c2, float4& c3)
{
    const int k = outer * 4 + U;
    if (k >= NK) return;                 // block-uniform guard (barrier-safe)
    const int n0 = 4 * k;
    const int bp = (k & 1) * 4;          // LDS quad

    // commit staged rows
    *reinterpret_cast<float4*>(&s[bp + 0][4 * cx.t]) = c0;
    *reinterpret_cast<float4*>(&s[bp + 1][4 * cx.t]) = c1;
    *reinterpret_cast<float4*>(&s[bp + 2][4 * cx.t]) = c2;
    *reinterpret_cast<float4*>(&s[bp + 3][4 * cx.t]) = c3;

    // prefetch next quad: rows n0+4..n0+7 = input rows r0+n0-2..r0+n0+1 (T14)
    if (k + 1 < NK) {
        const float* p0 = cx.xin + (size_t)reflect_idx(cx.r0 + n0 - 2, IMG_H) * IMG_W;
        const float* p1 = cx.xin + (size_t)reflect_idx(cx.r0 + n0 - 1, IMG_H) * IMG_W;
        const float* p2 = cx.xin + (size_t)reflect_idx(cx.r0 + n0 + 0, IMG_H) * IMG_W;
        const float* p3 = cx.xin + (size_t)reflect_idx(cx.r0 + n0 + 1, IMG_H) * IMG_W;
        c0 = *reinterpret_cast<const float4*>(p0 + 4 * cx.t);
        c1 = *reinterpret_cast<const float4*>(p1 + 4 * cx.t);
        c2 = *reinterpret_cast<const float4*>(p2 + 4 * cx.t);
        c3 = *reinterpret_cast<const float4*>(p3 + 4 * cx.t);
    }
    __syncthreads();

    // four H-filters into the rolling 16-slot window (slot of row n is n%16)
    w[(4 * U + 0) % 16] = h_filter(s[bp + 0], cx);
    w[(4 * U + 1) % 16] = h_filter(s[bp + 1], cx);
    w[(4 * U + 2) % 16] = h_filter(s[bp + 2], cx);
    w[(4 * U + 3) % 16] = h_filter(s[bp + 3], cx);

    // four V-filters -> output rows r0+n0-12 .. r0+n0-9
    if (n0 >= 12) {
        #pragma unroll
        for (int m = 0; m < 4; ++m) {
            float4 a = make_float4(0.f, 0.f, 0.f, 0.f);
            #pragma unroll
            for (int j = 0; j < KS; ++j) {
                // row (n0-12+m)+j -> slot (4U+m+4+j)%16  (-12 == +4 mod 16)
                const float4 v = w[(4 * U + m + 4 + j) % 16];
                a.x += cx.g[j] * v.x;
                a.y += cx.g[j] * v.y;
                a.z += cx.g[j] * v.z;
                a.w += cx.g[j] * v.w;
            }
            *reinterpret_cast<float4*>(
                cx.o + (size_t)(cx.r0 + n0 - 12 + m) * IMG_W + 4 * cx.t) = a;
        }
    }
}

// No launch-bounds min-waves (R2: VGPR cap -> spill). Expect ~120 VGPR (<128).
__global__ __launch_bounds__(256) void gauss_blur_stream(
    const float* __restrict__ x, const float* __restrict__ k2d,
    float* __restrict__ out)
{
    __shared__ float s[8][IMG_W];   // 32768 B: two ping-pong row QUADS

    Ctx cx;
    cx.t  = threadIdx.x;
    cx.r0 = blockIdx.x * TY;
    const int img = blockIdx.y;
    cx.xin = x + (size_t)img * IMG_H * IMG_W;
    cx.o   = out + (size_t)img * IMG_H * IMG_W;
    cx.interior = (cx.t >= 2) && (cx.t <= 253);

    // 1D taps: k2d = outer(g,g) exactly, g[i] = k2d[i][6]/sqrt(k2d[6][6])
    {
        float c   = k2d[HALF * KS + HALF];
        float inv = 1.0f / sqrtf(c);
        #pragma unroll
        for (int j = 0; j < KS; ++j) cx.g[j] = k2d[j * KS + HALF] * inv;
    }

    // preload rows 0..3 (input rows r0-6 .. r0-3, reflected)
    float4 c0 = *reinterpret_cast<const float4*>(
        cx.xin + (size_t)reflect_idx(cx.r0 - 6, IMG_H) * IMG_W + 4 * cx.t);
    float4 c1 = *reinterpret_cast<const float4*>(
        cx.xin + (size_t)reflect_idx(cx.r0 - 5, IMG_H) * IMG_W + 4 * cx.t);
    float4 c2 = *reinterpret_cast<const float4*>(
        cx.xin + (size_t)reflect_idx(cx.r0 - 4, IMG_H) * IMG_W + 4 * cx.t);
    float4 c3 = *reinterpret_cast<const float4*>(
        cx.xin + (size_t)reflect_idx(cx.r0 - 3, IMG_H) * IMG_W + 4 * cx.t);

    float4 w[16];
    for (int outer = 0; outer < 3; ++outer) {   // 3*4 = 12 bodies, guard k<11
        body4<0>(outer, cx, s, w, c0, c1, c2, c3);
        body4<1>(outer, cx, s, w, c0, c1, c2, c3);
        body4<2>(outer, cx, s, w, c0, c1, c2, c3);
        body4<3>(outer, cx, s, w, c0, c1, c2, c3);
    }
}

extern "C" void kernel_launch(void* const* d_in, const int* in_sizes, int n_in,
                              void* d_out, int out_size, void* d_ws, size_t ws_size,
                              hipStream_t stream) {
    const float* x   = (const float*)d_in[0];
    const float* k2d = (const float*)d_in[1];
    float*       out = (float*)d_out;

    dim3 grid(IMG_H / TY, 32);   // 32 strips x 32 images = 1024 blocks
    gauss_blur_stream<<<grid, 256, 0, stream>>>(x, k2d, out);
}